// Round 19
// baseline (173.952 us; speedup 1.0000x reference)
//
#include <hip/hip_runtime.h>
#include <hip/hip_bf16.h>

using bf16 = __hip_bfloat16;
typedef __attribute__((ext_vector_type(8))) short bf16x8;   // 8 bf16 in 4 VGPRs (MFMA A/B frag)
typedef __attribute__((ext_vector_type(4))) short short4v;  // 4 bf16 packed store
typedef __attribute__((ext_vector_type(4))) float f32x4;    // MFMA C/D frag

#define MFMA(a, b, c) __builtin_amdgcn_mfma_f32_16x16x32_bf16((a), (b), (c), 0, 0, 0)

// Problem constants
#define S_LEN 4096
#define D_MODEL 256
#define NH 4
#define HD 64
#define NTOK 8192   // B*S
#define PROW 72     // P-tile LDS row stride in shorts (proven R8)
#define XROW 264    // staged-tile LDS row stride in shorts (proven R12)
#define TROWV 72    // V transpose-buffer row stride (R16)
#define SM_SHIFT 16.0f  // static softmax shift (proven R10); partials over
                        // disjoint key ranges combine by pure addition (R18)

// DTYPE RESOLUTION (R3-R8 evidence): inputs and output are FP32.

static __device__ __forceinline__ short f2bf(float f) {
  bf16 h = __float2bfloat16(f);
  return *reinterpret_cast<short*>(&h);
}

// bf16 bit-pattern (as short) -> float, no addressing.
static __device__ __forceinline__ float bf2f(short s) {
  const unsigned int u = ((unsigned int)(unsigned short)s) << 16;
  return __builtin_bit_cast(float, u);
}

// Async 1KB global->LDS copy, source-swizzled (proven R11).
static __device__ __forceinline__ void stage1k(const bf16* g, short* l, int lane) {
  const int ri = lane >> 3;
  const int ci = lane & 7;
  const bf16* gp = g + ri * 64 + ((ci ^ ri) << 3);
  __builtin_amdgcn_global_load_lds(
      (const __attribute__((address_space(1))) void*)gp,
      (__attribute__((address_space(3))) void*)l, 16, 0, 0);
}

// ---------------------------------------------------------------------------
// Kernel 0: pack the 4 weight matrices into FRAGMENT-MAJOR bf16 (proven R13).
// ---------------------------------------------------------------------------
__global__ __launch_bounds__(256) void pack_w(
    const float* __restrict__ wq, const float* __restrict__ wk,
    const float* __restrict__ wv, const float* __restrict__ wo,
    bf16* __restrict__ wpk) {
  const int mat = blockIdx.x >> 4;
  const int nt  = blockIdx.x & 15;
  const float* W = (mat == 0) ? wq : (mat == 1) ? wk : (mat == 2) ? wv : wo;
  bf16* dst = wpk + ((size_t)(mat * 16 + nt)) * 4096;
#pragma unroll
  for (int it = 0; it < 16; ++it) {
    const int idx = it * 256 + threadIdx.x;
    const int kkt = idx >> 9;
    const int rem = idx & 511;
    const int L = rem >> 3, j = rem & 7;
    const int row = nt * 16 + (L & 15);
    const int col = kkt * 32 + (L >> 4) * 8 + j;
    dst[kkt * 512 + rem] = __float2bfloat16(W[(size_t)row * D_MODEL + col]);
  }
}

// ---------------------------------------------------------------------------
// Kernel 1: QKV projections — R16 version (staged X, packed W, LDS-transpose
// vectorized stores; validated).
// ---------------------------------------------------------------------------
__global__ __launch_bounds__(256) void qkv_proj(
    const float* __restrict__ q_in, const float* __restrict__ k_in, const float* __restrict__ v_in,
    const float* __restrict__ bq_, const float* __restrict__ bk_, const float* __restrict__ bv_,
    const bf16* __restrict__ wpk,
    bf16* __restrict__ qg, bf16* __restrict__ kg, bf16* __restrict__ vtg) {
  const int tid  = threadIdx.x;
  const int wave = tid >> 6;
  const int lane = tid & 63;
  const int quad = lane >> 4;
  const int l16  = lane & 15;
  const int z  = blockIdx.y;
  const int m0 = blockIdx.x * 64;

  const float* X  = (z == 0) ? q_in : (z == 1) ? k_in : v_in;
  const float* Bp = (z == 0) ? bq_  : (z == 1) ? bk_  : bv_;
  const bf16* wp = wpk + (size_t)z * 65536;

  __shared__ short xs[64 * XROW];
  __shared__ short tbuf[256 * TROWV];

#pragma unroll
  for (int it = 0; it < 16; ++it) {
    const int idx = it * 256 + tid;
    const int row = idx >> 6;
    const int c4  = idx & 63;
    const float4 f = *(const float4*)(X + (size_t)(m0 + row) * D_MODEL + c4 * 4);
    short4v s;
    s[0] = f2bf(f.x); s[1] = f2bf(f.y); s[2] = f2bf(f.z); s[3] = f2bf(f.w);
    *(short4v*)&xs[row * XROW + c4 * 4] = s;
  }
  __syncthreads();

  f32x4 acc[4][4] = {};

  if (z < 2) {
    for (int kki = 0; kki < 8; ++kki) {
      const int kk = kki * 32;
      bf16x8 bfr[4];
#pragma unroll
      for (int nt = 0; nt < 4; ++nt)
        bfr[nt] = *(const bf16x8*)(wp + ((wave * 4 + nt) * 8 + kki) * 512 + lane * 8);
#pragma unroll
      for (int ms = 0; ms < 4; ++ms) {
        bf16x8 a = *(const bf16x8*)&xs[(ms * 16 + l16) * XROW + kk + quad * 8];
#pragma unroll
        for (int nt = 0; nt < 4; ++nt) acc[ms][nt] = MFMA(a, bfr[nt], acc[ms][nt]);
      }
    }
    bf16* dst = (z == 0) ? qg : kg;
    const float scale = (z == 0) ? 0.125f : 1.0f;
#pragma unroll
    for (int nt = 0; nt < 4; ++nt) {
      const int o = wave * 64 + nt * 16 + l16;
      const float bias = Bp[o];
#pragma unroll
      for (int ms = 0; ms < 4; ++ms)
#pragma unroll
        for (int r = 0; r < 4; ++r)
          tbuf[(ms * 16 + quad * 4 + r) * XROW + o] =
              f2bf((acc[ms][nt][r] + bias) * scale);
    }
    asm volatile("" ::: "memory");
    const int h = wave;
    const int b_ = m0 >> 12, s0 = m0 & 4095;
    bf16* base = dst + ((size_t)(b_ * NH + h) * S_LEN + s0) * HD;
#pragma unroll
    for (int it = 0; it < 8; ++it) {
      const int s  = it * 8 + (lane >> 3);
      const int ch = (lane & 7) * 8;
      bf16x8 v = *(const bf16x8*)&tbuf[s * XROW + h * 64 + ch];
      *(bf16x8*)(base + (size_t)s * HD + ch) = v;
    }
  } else {
    for (int kki = 0; kki < 8; ++kki) {
      const int kk = kki * 32;
      bf16x8 bx[4];
#pragma unroll
      for (int ts = 0; ts < 4; ++ts)
        bx[ts] = *(const bf16x8*)&xs[(ts * 16 + l16) * XROW + kk + quad * 8];
#pragma unroll
      for (int ot = 0; ot < 4; ++ot) {
        bf16x8 aw = *(const bf16x8*)(wp + ((wave * 4 + ot) * 8 + kki) * 512 + lane * 8);
#pragma unroll
        for (int ts = 0; ts < 4; ++ts) acc[ot][ts] = MFMA(aw, bx[ts], acc[ot][ts]);
      }
    }
#pragma unroll
    for (int ot = 0; ot < 4; ++ot)
#pragma unroll
      for (int r = 0; r < 4; ++r) {
        const int o = wave * 64 + ot * 16 + quad * 4 + r;
        const float bias = Bp[o];
#pragma unroll
        for (int ts = 0; ts < 4; ++ts)
          tbuf[o * TROWV + ts * 16 + l16] = f2bf(acc[ot][ts][r] + bias);
      }
    asm volatile("" ::: "memory");
    const int h = wave;
    const int b_ = m0 >> 12;
    const int jt = (m0 & 4095) >> 6;
    bf16* vbase = vtg + ((size_t)((b_ * NH + h) * (S_LEN / 64) + jt)) * HD * 64;
#pragma unroll
    for (int it = 0; it < 8; ++it) {
      const int hd = it * 8 + (lane >> 3);
      const int jj = (lane & 7) * 8;
      bf16x8 v = *(const bf16x8*)&tbuf[(h * 64 + hd) * TROWV + jj];
      *(bf16x8*)(vbase + (size_t)hd * 64 + jj) = v;
    }
  }
}

// ---------------------------------------------------------------------------
// Kernel 2: flash attention (R19): 2-wave blocks, single-subtile rounds,
// 4 blocks/CU. R18 (4-wave, 2-subtile, 2 blocks/CU) measured ~3k cyc/round
// of exposed stall beyond the LDS-pipe work; quadrupling independent barrier
// domains (LDS 74.75 -> 36.5 KB, grid 512 -> 1024 via same KV-split-2)
// overlaps those stalls. Per-wave staging rate and 8 waves/CU preserved
// (fixes both R14 regression causes). 2 q-sets/wave kept (R18's proven
// LDS-traffic cut). Static-shift partials, pure-addition combine.
// Carried (proven): XCD-aware bh=blockIdx&7, global_load_lds staging w/
// source swizzle, barrier-free wave-private P round-trip, PROW=72.
// ---------------------------------------------------------------------------
__global__ __launch_bounds__(128) void attn_fwd(
    const bf16* qg, const bf16* kg, const bf16* vtg,
    bf16* part0, bf16* part1, float* lbuf) {
  const int wave = threadIdx.x >> 6;   // 0..1
  const int lane = threadIdx.x & 63;
  const int quad = lane >> 4;
  const int l16  = lane & 15;
  const int bh   = blockIdx.x & 7;        // XCD-aligned under %8 round-robin
  const int half = (blockIdx.x >> 3) & 1; // key range half
  const int q0   = (blockIdx.x >> 4) * 64;

  const bf16* qb = qg  + (size_t)bh * S_LEN * HD;
  const bf16* kb = kg  + (size_t)bh * S_LEN * HD;
  const bf16* vb = vtg + (size_t)bh * S_LEN * HD;  // tile-major: 64 x 4096

  __shared__ short kbuf[2][4096];   // 8KB per buffer
  __shared__ short vbuf[2][4096];
  __shared__ short p_lds[2 * 16 * PROW];

  // Two 16-row Q fragment sets per wave (64 rows per block).
  bf16x8 qf[2][2];
#pragma unroll
  for (int qs = 0; qs < 2; ++qs) {
    const bf16* qrow = qb + (size_t)(q0 + wave * 32 + qs * 16 + l16) * HD;
    qf[qs][0] = *(const bf16x8*)(qrow + quad * 8);
    qf[qs][1] = *(const bf16x8*)(qrow + 32 + quad * 8);
  }

  float l_acc[2] = {0.f, 0.f};
  f32x4 oT[2][4] = {};
  const int pb = wave * (16 * PROW) + l16 * PROW;
  const int sw = l16 & 7;
  const int c0 = wave * 4;             // this wave's staging chunks: c0..c0+3

#define STAGE(b, r)                                                         \
  {                                                                         \
    const bf16* kt = kb + (size_t)(r) * 4096;                               \
    const bf16* vt_ = vb + (size_t)(r) * 4096;                              \
    _Pragma("unroll")                                                       \
    for (int q = 0; q < 4; ++q) {                                           \
      stage1k(kt + (c0 + q) * 512, &kbuf[b][(c0 + q) * 512], lane);         \
      stage1k(vt_ + (c0 + q) * 512, &vbuf[b][(c0 + q) * 512], lane);        \
    }                                                                       \
  }

  const int t0 = half * 32, t1 = t0 + 32;   // 32 tiles = 2048 keys per half
  STAGE(0, t0)

  for (int t = t0; t < t1; ++t) {
    const int buf = t & 1;
    __syncthreads();
    if (t + 1 < t1) STAGE(buf ^ 1, t + 1)

    // K fragments once, feed both q-sets.
    bf16x8 kf[4][2];
#pragma unroll
    for (int ct = 0; ct < 4; ++ct) {
      const int rbase = (ct * 16 + l16) * 64;
      kf[ct][0] = *(const bf16x8*)&kbuf[buf][rbase + ((quad ^ sw) << 3)];
      kf[ct][1] = *(const bf16x8*)&kbuf[buf][rbase + (((quad + 4) ^ sw) << 3)];
    }

    f32x4 st[2][4] = {};
#pragma unroll
    for (int qs = 0; qs < 2; ++qs)
#pragma unroll
      for (int ct = 0; ct < 4; ++ct) {
        st[qs][ct] = MFMA(kf[ct][0], qf[qs][0], st[qs][ct]);
        st[qs][ct] = MFMA(kf[ct][1], qf[qs][1], st[qs][ct]);
      }

    // V fragments once, feed both q-sets.
    bf16x8 vf[4][2];
#pragma unroll
    for (int tt = 0; tt < 4; ++tt) {
      const int rbase = (tt * 16 + l16) * 64;
      vf[tt][0] = *(const bf16x8*)&vbuf[buf][rbase + ((quad ^ sw) << 3)];
      vf[tt][1] = *(const bf16x8*)&vbuf[buf][rbase + (((quad + 4) ^ sw) << 3)];
    }

#pragma unroll
    for (int qs = 0; qs < 2; ++qs) {
#pragma unroll
      for (int ct = 0; ct < 4; ++ct)
#pragma unroll
        for (int r = 0; r < 4; ++r) {
          const float p = __expf(st[qs][ct][r] - SM_SHIFT);
          st[qs][ct][r] = p;
          l_acc[qs] += p;
        }

      asm volatile("" ::: "memory");  // WAR
#pragma unroll
      for (int ct = 0; ct < 4; ++ct) {
        short4v pk;
        pk[0] = f2bf(st[qs][ct][0]);
        pk[1] = f2bf(st[qs][ct][1]);
        pk[2] = f2bf(st[qs][ct][2]);
        pk[3] = f2bf(st[qs][ct][3]);
        *(short4v*)&p_lds[pb + ct * 16 + quad * 4] = pk;
      }
      asm volatile("" ::: "memory");  // RAW
      bf16x8 bp0 = *(const bf16x8*)&p_lds[pb + quad * 8];
      bf16x8 bp1 = *(const bf16x8*)&p_lds[pb + 32 + quad * 8];

#pragma unroll
      for (int tt = 0; tt < 4; ++tt) {
        oT[qs][tt] = MFMA(vf[tt][0], bp0, oT[qs][tt]);
        oT[qs][tt] = MFMA(vf[tt][1], bp1, oT[qs][tt]);
      }
    }
  }
#undef STAGE

  // Emit UNNORMALIZED partials (static shift -> partials add across halves).
  bf16* part = half ? part1 : part0;
  const int b_ = bh >> 2, h = bh & 3;
#pragma unroll
  for (int qs = 0; qs < 2; ++qs) {
    float l = l_acc[qs];
    l += __shfl_xor(l, 16);
    l += __shfl_xor(l, 32);
    const int srow = q0 + wave * 32 + qs * 16 + l16;
    if (quad == 0)  // one writer per token
      lbuf[half * 32768 + bh * 4096 + srow] = l;
    bf16* ob = part + ((size_t)(b_ * S_LEN + srow)) * D_MODEL + h * HD;
#pragma unroll
    for (int t = 0; t < 4; ++t) {
      short4v pk;
#pragma unroll
      for (int r = 0; r < 4; ++r) pk[r] = f2bf(oT[qs][t][r]);
      *(short4v*)(ob + t * 16 + quad * 4) = pk;
    }
  }
}

// ---------------------------------------------------------------------------
// Kernel 3: out-projection + LayerNorm with FUSED partial combine (R19):
// staging reads part0+part1 and normalizes by 1/(l0+l1) — removes the
// separate attn_combine launch and its 4MB read+write round trip.
// GEMM + LN parts unchanged (proven R13).
// ---------------------------------------------------------------------------
__global__ __launch_bounds__(256) void out_ln(
    const bf16* __restrict__ part0, const bf16* __restrict__ part1,
    const float* __restrict__ lbuf, const bf16* __restrict__ wpk,
    const float* __restrict__ bo_, const float* __restrict__ gamma,
    const float* __restrict__ beta, float* __restrict__ out) {
  const int tid = threadIdx.x;
  const int wave = tid >> 6;
  const int lane = tid & 63;
  const int quad = lane >> 4;
  const int l16  = lane & 15;
  const int t0 = blockIdx.x * 16;
  const bf16* wp = wpk + (size_t)3 * 65536;

  __shared__ short as_[16 * XROW];
  __shared__ float ybuf[16 * 256];
  __shared__ float mu_s[16], rs_s[16];

  // Stage + combine: attn = (P0+P1) / (l0+l1), per 16B chunk.
#pragma unroll
  for (int it = 0; it < 2; ++it) {
    const int idx = it * 256 + tid;
    const int row = idx >> 5;
    const int c8  = idx & 31;
    const int token = t0 + row;
    const int h = c8 >> 3;
    const int bh = (token >> 12) * NH + h;
    const int s = token & 4095;
    const float li = 1.0f / (lbuf[bh * 4096 + s] + lbuf[32768 + bh * 4096 + s]);
    const size_t gidx = (size_t)token * D_MODEL + c8 * 8;
    bf16x8 a = *(const bf16x8*)(part0 + gidx);
    bf16x8 b = *(const bf16x8*)(part1 + gidx);
    bf16x8 o;
#pragma unroll
    for (int j = 0; j < 8; ++j)
      o[j] = f2bf((bf2f(a[j]) + bf2f(b[j])) * li);
    *(bf16x8*)&as_[row * XROW + c8 * 8] = o;
  }
  __syncthreads();

  f32x4 acc[4] = {};
  for (int kki = 0; kki < 8; ++kki) {
    const int kk = kki * 32;
    bf16x8 a = *(const bf16x8*)&as_[l16 * XROW + kk + quad * 8];
#pragma unroll
    for (int nt = 0; nt < 4; ++nt) {
      bf16x8 b = *(const bf16x8*)(wp + ((wave * 4 + nt) * 8 + kki) * 512 + lane * 8);
      acc[nt] = MFMA(a, b, acc[nt]);
    }
  }
#pragma unroll
  for (int nt = 0; nt < 4; ++nt) {
    const int o = wave * 64 + nt * 16 + l16;
    const float bias = bo_[o];
#pragma unroll
    for (int r = 0; r < 4; ++r) ybuf[(quad * 4 + r) * 256 + o] = acc[nt][r] + bias;
  }
  __syncthreads();

#pragma unroll
  for (int rr = 0; rr < 4; ++rr) {
    const int row = wave * 4 + rr;
    float s1 = 0.f, s2 = 0.f;
#pragma unroll
    for (int c = 0; c < 4; ++c) {
      const float v = ybuf[row * 256 + c * 64 + lane];
      s1 += v;
      s2 += v * v;
    }
#pragma unroll
    for (int m = 32; m >= 1; m >>= 1) {
      s1 += __shfl_xor(s1, m);
      s2 += __shfl_xor(s2, m);
    }
    if (lane == 0) {
      const float mu = s1 * (1.f / 256.f);
      const float var = s2 * (1.f / 256.f) - mu * mu;
      mu_s[row] = mu;
      rs_s[row] = rsqrtf(var + 1e-5f);
    }
  }
  __syncthreads();

  const float g  = gamma[tid];
  const float be = beta[tid];
#pragma unroll 4
  for (int row = 0; row < 16; ++row) {
    const float v = ybuf[row * 256 + tid];
    const float o = (v - mu_s[row]) * rs_s[row] * g + be;
    out[(size_t)(t0 + row) * D_MODEL + tid] = o;
  }
}

// ---------------------------------------------------------------------------
extern "C" void kernel_launch(void* const* d_in, const int* in_sizes, int n_in,
                              void* d_out, int out_size, void* d_ws, size_t ws_size,
                              hipStream_t stream) {
  const float* q_in  = (const float*)d_in[0];
  const float* k_in  = (const float*)d_in[1];
  const float* v_in  = (const float*)d_in[2];
  const float* wq    = (const float*)d_in[3];
  const float* bq    = (const float*)d_in[4];
  const float* wk    = (const float*)d_in[5];
  const float* bk    = (const float*)d_in[6];
  const float* wv    = (const float*)d_in[7];
  const float* bv    = (const float*)d_in[8];
  const float* wo    = (const float*)d_in[9];
  const float* bo    = (const float*)d_in[10];
  const float* gamma = (const float*)d_in[11];
  const float* beta  = (const float*)d_in[12];
  float* out = (float*)d_out;

  // qg/kg staged in d_out (proven). ws: vtt 4MB | part0 4MB | part1 4MB |
  // wpk 512KB | lbuf 256KB = 12.75 MB (proven fits in R18).
  const size_t SEG = (size_t)NTOK * D_MODEL;  // 2,097,152 elements
  bf16* qg    = (bf16*)d_out;
  bf16* kg    = (bf16*)d_out + SEG;
  bf16* vtt   = (bf16*)d_ws;
  bf16* part0 = (bf16*)d_ws + SEG;
  bf16* part1 = (bf16*)d_ws + 2 * SEG;
  bf16* wpk   = (bf16*)d_ws + 3 * SEG;  // 262144 elements
  float* lbuf = (float*)((bf16*)d_ws + 3 * SEG + 262144);  // 65536 floats

  pack_w<<<dim3(64), 256, 0, stream>>>(wq, wk, wv, wo, wpk);
  qkv_proj<<<dim3(128, 3), 256, 0, stream>>>(q_in, k_in, v_in, bq, bk, bv, wpk,
                                             qg, kg, vtt);
  attn_fwd<<<dim3(1024), 128, 0, stream>>>(qg, kg, vtt, part0, part1, lbuf);
  out_ln<<<dim3(512), 256, 0, stream>>>(part0, part1, lbuf, wpk, bo, gamma, beta, out);
}

// Round 20
// 169.237 us; speedup vs baseline: 1.0279x; 1.0279x over previous
//
#include <hip/hip_runtime.h>
#include <hip/hip_bf16.h>

using bf16 = __hip_bfloat16;
typedef __attribute__((ext_vector_type(8))) short bf16x8;   // 8 bf16 in 4 VGPRs (MFMA A/B frag)
typedef __attribute__((ext_vector_type(4))) short short4v;  // 4 bf16 packed store
typedef __attribute__((ext_vector_type(4))) float f32x4;    // MFMA C/D frag

#define MFMA(a, b, c) __builtin_amdgcn_mfma_f32_16x16x32_bf16((a), (b), (c), 0, 0, 0)

// Problem constants
#define S_LEN 4096
#define D_MODEL 256
#define NH 4
#define HD 64
#define NTOK 8192   // B*S
#define PROW 72     // P-tile LDS row stride in shorts (proven R8)
#define XROW 264    // staged-tile LDS row stride in shorts (proven R12)
#define TROWV 72    // V transpose-buffer row stride (R16)
#define SM_SHIFT 16.0f  // static softmax shift (proven R10); partials over
                        // disjoint key ranges combine by pure addition (R18)

// DTYPE RESOLUTION (R3-R8 evidence): inputs and output are FP32.

static __device__ __forceinline__ short f2bf(float f) {
  bf16 h = __float2bfloat16(f);
  return *reinterpret_cast<short*>(&h);
}

// bf16 bit-pattern (as short) -> float, no addressing.
static __device__ __forceinline__ float bf2f(short s) {
  const unsigned int u = ((unsigned int)(unsigned short)s) << 16;
  return __builtin_bit_cast(float, u);
}

// Async 1KB global->LDS copy, source-swizzled (proven R11).
static __device__ __forceinline__ void stage1k(const bf16* g, short* l, int lane) {
  const int ri = lane >> 3;
  const int ci = lane & 7;
  const bf16* gp = g + ri * 64 + ((ci ^ ri) << 3);
  __builtin_amdgcn_global_load_lds(
      (const __attribute__((address_space(1))) void*)gp,
      (__attribute__((address_space(3))) void*)l, 16, 0, 0);
}

// ---------------------------------------------------------------------------
// Kernel 0: pack the 4 weight matrices into FRAGMENT-MAJOR bf16 (proven R13).
// ---------------------------------------------------------------------------
__global__ __launch_bounds__(256) void pack_w(
    const float* __restrict__ wq, const float* __restrict__ wk,
    const float* __restrict__ wv, const float* __restrict__ wo,
    bf16* __restrict__ wpk) {
  const int mat = blockIdx.x >> 4;
  const int nt  = blockIdx.x & 15;
  const float* W = (mat == 0) ? wq : (mat == 1) ? wk : (mat == 2) ? wv : wo;
  bf16* dst = wpk + ((size_t)(mat * 16 + nt)) * 4096;
#pragma unroll
  for (int it = 0; it < 16; ++it) {
    const int idx = it * 256 + threadIdx.x;
    const int kkt = idx >> 9;
    const int rem = idx & 511;
    const int L = rem >> 3, j = rem & 7;
    const int row = nt * 16 + (L & 15);
    const int col = kkt * 32 + (L >> 4) * 8 + j;
    dst[kkt * 512 + rem] = __float2bfloat16(W[(size_t)row * D_MODEL + col]);
  }
}

// ---------------------------------------------------------------------------
// Kernel 1: QKV projections — R16 version (staged X, packed W, LDS-transpose
// vectorized stores; validated).
// ---------------------------------------------------------------------------
__global__ __launch_bounds__(256) void qkv_proj(
    const float* __restrict__ q_in, const float* __restrict__ k_in, const float* __restrict__ v_in,
    const float* __restrict__ bq_, const float* __restrict__ bk_, const float* __restrict__ bv_,
    const bf16* __restrict__ wpk,
    bf16* __restrict__ qg, bf16* __restrict__ kg, bf16* __restrict__ vtg) {
  const int tid  = threadIdx.x;
  const int wave = tid >> 6;
  const int lane = tid & 63;
  const int quad = lane >> 4;
  const int l16  = lane & 15;
  const int z  = blockIdx.y;
  const int m0 = blockIdx.x * 64;

  const float* X  = (z == 0) ? q_in : (z == 1) ? k_in : v_in;
  const float* Bp = (z == 0) ? bq_  : (z == 1) ? bk_  : bv_;
  const bf16* wp = wpk + (size_t)z * 65536;

  __shared__ short xs[64 * XROW];
  __shared__ short tbuf[256 * TROWV];

#pragma unroll
  for (int it = 0; it < 16; ++it) {
    const int idx = it * 256 + tid;
    const int row = idx >> 6;
    const int c4  = idx & 63;
    const float4 f = *(const float4*)(X + (size_t)(m0 + row) * D_MODEL + c4 * 4);
    short4v s;
    s[0] = f2bf(f.x); s[1] = f2bf(f.y); s[2] = f2bf(f.z); s[3] = f2bf(f.w);
    *(short4v*)&xs[row * XROW + c4 * 4] = s;
  }
  __syncthreads();

  f32x4 acc[4][4] = {};

  if (z < 2) {
    for (int kki = 0; kki < 8; ++kki) {
      const int kk = kki * 32;
      bf16x8 bfr[4];
#pragma unroll
      for (int nt = 0; nt < 4; ++nt)
        bfr[nt] = *(const bf16x8*)(wp + ((wave * 4 + nt) * 8 + kki) * 512 + lane * 8);
#pragma unroll
      for (int ms = 0; ms < 4; ++ms) {
        bf16x8 a = *(const bf16x8*)&xs[(ms * 16 + l16) * XROW + kk + quad * 8];
#pragma unroll
        for (int nt = 0; nt < 4; ++nt) acc[ms][nt] = MFMA(a, bfr[nt], acc[ms][nt]);
      }
    }
    bf16* dst = (z == 0) ? qg : kg;
    const float scale = (z == 0) ? 0.125f : 1.0f;
#pragma unroll
    for (int nt = 0; nt < 4; ++nt) {
      const int o = wave * 64 + nt * 16 + l16;
      const float bias = Bp[o];
#pragma unroll
      for (int ms = 0; ms < 4; ++ms)
#pragma unroll
        for (int r = 0; r < 4; ++r)
          tbuf[(ms * 16 + quad * 4 + r) * XROW + o] =
              f2bf((acc[ms][nt][r] + bias) * scale);
    }
    asm volatile("" ::: "memory");
    const int h = wave;
    const int b_ = m0 >> 12, s0 = m0 & 4095;
    bf16* base = dst + ((size_t)(b_ * NH + h) * S_LEN + s0) * HD;
#pragma unroll
    for (int it = 0; it < 8; ++it) {
      const int s  = it * 8 + (lane >> 3);
      const int ch = (lane & 7) * 8;
      bf16x8 v = *(const bf16x8*)&tbuf[s * XROW + h * 64 + ch];
      *(bf16x8*)(base + (size_t)s * HD + ch) = v;
    }
  } else {
    for (int kki = 0; kki < 8; ++kki) {
      const int kk = kki * 32;
      bf16x8 bx[4];
#pragma unroll
      for (int ts = 0; ts < 4; ++ts)
        bx[ts] = *(const bf16x8*)&xs[(ts * 16 + l16) * XROW + kk + quad * 8];
#pragma unroll
      for (int ot = 0; ot < 4; ++ot) {
        bf16x8 aw = *(const bf16x8*)(wp + ((wave * 4 + ot) * 8 + kki) * 512 + lane * 8);
#pragma unroll
        for (int ts = 0; ts < 4; ++ts) acc[ot][ts] = MFMA(aw, bx[ts], acc[ot][ts]);
      }
    }
#pragma unroll
    for (int ot = 0; ot < 4; ++ot)
#pragma unroll
      for (int r = 0; r < 4; ++r) {
        const int o = wave * 64 + ot * 16 + quad * 4 + r;
        const float bias = Bp[o];
#pragma unroll
        for (int ts = 0; ts < 4; ++ts)
          tbuf[o * TROWV + ts * 16 + l16] = f2bf(acc[ot][ts][r] + bias);
      }
    asm volatile("" ::: "memory");
    const int h = wave;
    const int b_ = m0 >> 12;
    const int jt = (m0 & 4095) >> 6;
    bf16* vbase = vtg + ((size_t)((b_ * NH + h) * (S_LEN / 64) + jt)) * HD * 64;
#pragma unroll
    for (int it = 0; it < 8; ++it) {
      const int hd = it * 8 + (lane >> 3);
      const int jj = (lane & 7) * 8;
      bf16x8 v = *(const bf16x8*)&tbuf[(h * 64 + hd) * TROWV + jj];
      *(bf16x8*)(vbase + (size_t)hd * 64 + jj) = v;
    }
  }
}

// ---------------------------------------------------------------------------
// Kernel 2: flash attention — EXACT R18 (measured best, 60.9 us):
// 4-wave blocks, 2 q-sets/wave (32 q-rows/wave, 128/block), KV-split-2,
// 2-subtile double-buffered rounds, grid 512 (2 blocks/CU, 8 waves/CU).
// R19's 2-wave/4-block variant regressed to 67 us (and R14's to 109):
// wider blocks win — do not narrow again.
// Carried (proven): XCD-aware bh=blockIdx&7, global_load_lds staging w/
// source swizzle, static-shift softmax, barrier-free wave-private P
// round-trip, PROW=72.
// ---------------------------------------------------------------------------
__global__ __launch_bounds__(256) void attn_fwd(
    const bf16* qg, const bf16* kg, const bf16* vtg,
    bf16* part0, bf16* part1, float* lbuf) {
  const int wave = threadIdx.x >> 6;
  const int lane = threadIdx.x & 63;
  const int quad = lane >> 4;
  const int l16  = lane & 15;
  const int bh   = blockIdx.x & 7;        // XCD-aligned under %8 round-robin
  const int half = (blockIdx.x >> 3) & 1; // key range half
  const int q0   = (blockIdx.x >> 4) * 128;

  const bf16* qb = qg  + (size_t)bh * S_LEN * HD;
  const bf16* kb = kg  + (size_t)bh * S_LEN * HD;
  const bf16* vb = vtg + (size_t)bh * S_LEN * HD;  // tile-major: 64 x 4096

  __shared__ short kbuf[2][2 * 4096];   // 16KB per buffer
  __shared__ short vbuf[2][2 * 4096];
  __shared__ short p_lds[4 * 16 * PROW];

  // Two 16-row Q fragment sets per wave.
  bf16x8 qf[2][2];
#pragma unroll
  for (int qs = 0; qs < 2; ++qs) {
    const bf16* qrow = qb + (size_t)(q0 + wave * 32 + qs * 16 + l16) * HD;
    qf[qs][0] = *(const bf16x8*)(qrow + quad * 8);
    qf[qs][1] = *(const bf16x8*)(qrow + 32 + quad * 8);
  }

  float l_acc[2] = {0.f, 0.f};
  f32x4 oT[2][4] = {};
  const int pb = wave * (16 * PROW) + l16 * PROW;
  const int sw = l16 & 7;
  const int c0 = wave * 2;

#define STAGE_ROUND(b, r)                                                   \
  {                                                                         \
    _Pragma("unroll")                                                       \
    for (int sub = 0; sub < 2; ++sub) {                                     \
      const bf16* kt = kb + (size_t)(2 * (r) + sub) * 4096;                 \
      const bf16* vt_ = vb + (size_t)(2 * (r) + sub) * 4096;                \
      _Pragma("unroll")                                                     \
      for (int q = 0; q < 2; ++q) {                                         \
        stage1k(kt + (c0 + q) * 512, &kbuf[b][sub * 4096 + (c0 + q) * 512], lane); \
        stage1k(vt_ + (c0 + q) * 512, &vbuf[b][sub * 4096 + (c0 + q) * 512], lane); \
      }                                                                     \
    }                                                                       \
  }

  const int t0 = half * 16, t1 = t0 + 16;   // 16 rounds = 2048 keys
  STAGE_ROUND(0, t0)

  for (int t = t0; t < t1; ++t) {
    const int buf = t & 1;
    __syncthreads();
    if (t + 1 < t1) STAGE_ROUND(buf ^ 1, t + 1)

#pragma unroll
    for (int sub = 0; sub < 2; ++sub) {
      const short* kB = &kbuf[buf][sub * 4096];
      const short* vB = &vbuf[buf][sub * 4096];

      // K fragments once, feed both q-sets.
      bf16x8 kf[4][2];
#pragma unroll
      for (int ct = 0; ct < 4; ++ct) {
        const int rbase = (ct * 16 + l16) * 64;
        kf[ct][0] = *(const bf16x8*)&kB[rbase + ((quad ^ sw) << 3)];
        kf[ct][1] = *(const bf16x8*)&kB[rbase + (((quad + 4) ^ sw) << 3)];
      }

      f32x4 st[2][4] = {};
#pragma unroll
      for (int qs = 0; qs < 2; ++qs)
#pragma unroll
        for (int ct = 0; ct < 4; ++ct) {
          st[qs][ct] = MFMA(kf[ct][0], qf[qs][0], st[qs][ct]);
          st[qs][ct] = MFMA(kf[ct][1], qf[qs][1], st[qs][ct]);
        }

      // V fragments once, feed both q-sets.
      bf16x8 vf[4][2];
#pragma unroll
      for (int tt = 0; tt < 4; ++tt) {
        const int rbase = (tt * 16 + l16) * 64;
        vf[tt][0] = *(const bf16x8*)&vB[rbase + ((quad ^ sw) << 3)];
        vf[tt][1] = *(const bf16x8*)&vB[rbase + (((quad + 4) ^ sw) << 3)];
      }

#pragma unroll
      for (int qs = 0; qs < 2; ++qs) {
#pragma unroll
        for (int ct = 0; ct < 4; ++ct)
#pragma unroll
          for (int r = 0; r < 4; ++r) {
            const float p = __expf(st[qs][ct][r] - SM_SHIFT);
            st[qs][ct][r] = p;
            l_acc[qs] += p;
          }

        asm volatile("" ::: "memory");  // WAR
#pragma unroll
        for (int ct = 0; ct < 4; ++ct) {
          short4v pk;
          pk[0] = f2bf(st[qs][ct][0]);
          pk[1] = f2bf(st[qs][ct][1]);
          pk[2] = f2bf(st[qs][ct][2]);
          pk[3] = f2bf(st[qs][ct][3]);
          *(short4v*)&p_lds[pb + ct * 16 + quad * 4] = pk;
        }
        asm volatile("" ::: "memory");  // RAW
        bf16x8 bp0 = *(const bf16x8*)&p_lds[pb + quad * 8];
        bf16x8 bp1 = *(const bf16x8*)&p_lds[pb + 32 + quad * 8];

#pragma unroll
        for (int tt = 0; tt < 4; ++tt) {
          oT[qs][tt] = MFMA(vf[tt][0], bp0, oT[qs][tt]);
          oT[qs][tt] = MFMA(vf[tt][1], bp1, oT[qs][tt]);
        }
      }
    }
  }
#undef STAGE_ROUND

  // Emit UNNORMALIZED partials (static shift -> partials add across halves).
  bf16* part = half ? part1 : part0;
  const int b_ = bh >> 2, h = bh & 3;
#pragma unroll
  for (int qs = 0; qs < 2; ++qs) {
    float l = l_acc[qs];
    l += __shfl_xor(l, 16);
    l += __shfl_xor(l, 32);
    const int srow = q0 + wave * 32 + qs * 16 + l16;
    if (quad == 0)  // one writer per token
      lbuf[half * 32768 + bh * 4096 + srow] = l;
    bf16* ob = part + ((size_t)(b_ * S_LEN + srow)) * D_MODEL + h * HD;
#pragma unroll
    for (int t = 0; t < 4; ++t) {
      short4v pk;
#pragma unroll
      for (int r = 0; r < 4; ++r) pk[r] = f2bf(oT[qs][t][r]);
      *(short4v*)(ob + t * 16 + quad * 4) = pk;
    }
  }
}

// ---------------------------------------------------------------------------
// Kernel 3: out-projection + LayerNorm with FUSED partial combine (R19,
// kept): staging reads part0+part1 and normalizes by 1/(l0+l1) — no separate
// combine launch / round trip. GEMM + LN parts unchanged (proven R13).
// ---------------------------------------------------------------------------
__global__ __launch_bounds__(256) void out_ln(
    const bf16* __restrict__ part0, const bf16* __restrict__ part1,
    const float* __restrict__ lbuf, const bf16* __restrict__ wpk,
    const float* __restrict__ bo_, const float* __restrict__ gamma,
    const float* __restrict__ beta, float* __restrict__ out) {
  const int tid = threadIdx.x;
  const int wave = tid >> 6;
  const int lane = tid & 63;
  const int quad = lane >> 4;
  const int l16  = lane & 15;
  const int t0 = blockIdx.x * 16;
  const bf16* wp = wpk + (size_t)3 * 65536;

  __shared__ short as_[16 * XROW];
  __shared__ float ybuf[16 * 256];
  __shared__ float mu_s[16], rs_s[16];

  // Stage + combine: attn = (P0+P1) / (l0+l1), per 16B chunk.
#pragma unroll
  for (int it = 0; it < 2; ++it) {
    const int idx = it * 256 + tid;
    const int row = idx >> 5;
    const int c8  = idx & 31;
    const int token = t0 + row;
    const int h = c8 >> 3;
    const int bh = (token >> 12) * NH + h;
    const int s = token & 4095;
    const float li = 1.0f / (lbuf[bh * 4096 + s] + lbuf[32768 + bh * 4096 + s]);
    const size_t gidx = (size_t)token * D_MODEL + c8 * 8;
    bf16x8 a = *(const bf16x8*)(part0 + gidx);
    bf16x8 b = *(const bf16x8*)(part1 + gidx);
    bf16x8 o;
#pragma unroll
    for (int j = 0; j < 8; ++j)
      o[j] = f2bf((bf2f(a[j]) + bf2f(b[j])) * li);
    *(bf16x8*)&as_[row * XROW + c8 * 8] = o;
  }
  __syncthreads();

  f32x4 acc[4] = {};
  for (int kki = 0; kki < 8; ++kki) {
    const int kk = kki * 32;
    bf16x8 a = *(const bf16x8*)&as_[l16 * XROW + kk + quad * 8];
#pragma unroll
    for (int nt = 0; nt < 4; ++nt) {
      bf16x8 b = *(const bf16x8*)(wp + ((wave * 4 + nt) * 8 + kki) * 512 + lane * 8);
      acc[nt] = MFMA(a, b, acc[nt]);
    }
  }
#pragma unroll
  for (int nt = 0; nt < 4; ++nt) {
    const int o = wave * 64 + nt * 16 + l16;
    const float bias = bo_[o];
#pragma unroll
    for (int r = 0; r < 4; ++r) ybuf[(quad * 4 + r) * 256 + o] = acc[nt][r] + bias;
  }
  __syncthreads();

#pragma unroll
  for (int rr = 0; rr < 4; ++rr) {
    const int row = wave * 4 + rr;
    float s1 = 0.f, s2 = 0.f;
#pragma unroll
    for (int c = 0; c < 4; ++c) {
      const float v = ybuf[row * 256 + c * 64 + lane];
      s1 += v;
      s2 += v * v;
    }
#pragma unroll
    for (int m = 32; m >= 1; m >>= 1) {
      s1 += __shfl_xor(s1, m);
      s2 += __shfl_xor(s2, m);
    }
    if (lane == 0) {
      const float mu = s1 * (1.f / 256.f);
      const float var = s2 * (1.f / 256.f) - mu * mu;
      mu_s[row] = mu;
      rs_s[row] = rsqrtf(var + 1e-5f);
    }
  }
  __syncthreads();

  const float g  = gamma[tid];
  const float be = beta[tid];
#pragma unroll 4
  for (int row = 0; row < 16; ++row) {
    const float v = ybuf[row * 256 + tid];
    const float o = (v - mu_s[row]) * rs_s[row] * g + be;
    out[(size_t)(t0 + row) * D_MODEL + tid] = o;
  }
}

// ---------------------------------------------------------------------------
extern "C" void kernel_launch(void* const* d_in, const int* in_sizes, int n_in,
                              void* d_out, int out_size, void* d_ws, size_t ws_size,
                              hipStream_t stream) {
  const float* q_in  = (const float*)d_in[0];
  const float* k_in  = (const float*)d_in[1];
  const float* v_in  = (const float*)d_in[2];
  const float* wq    = (const float*)d_in[3];
  const float* bq    = (const float*)d_in[4];
  const float* wk    = (const float*)d_in[5];
  const float* bk    = (const float*)d_in[6];
  const float* wv    = (const float*)d_in[7];
  const float* bv    = (const float*)d_in[8];
  const float* wo    = (const float*)d_in[9];
  const float* bo    = (const float*)d_in[10];
  const float* gamma = (const float*)d_in[11];
  const float* beta  = (const float*)d_in[12];
  float* out = (float*)d_out;

  // qg/kg staged in d_out (proven). ws: vtt 4MB | part0 4MB | part1 4MB |
  // wpk 512KB | lbuf 256KB = 12.75 MB (proven fits).
  const size_t SEG = (size_t)NTOK * D_MODEL;  // 2,097,152 elements
  bf16* qg    = (bf16*)d_out;
  bf16* kg    = (bf16*)d_out + SEG;
  bf16* vtt   = (bf16*)d_ws;
  bf16* part0 = (bf16*)d_ws + SEG;
  bf16* part1 = (bf16*)d_ws + 2 * SEG;
  bf16* wpk   = (bf16*)d_ws + 3 * SEG;  // 262144 elements
  float* lbuf = (float*)((bf16*)d_ws + 3 * SEG + 262144);  // 65536 floats

  pack_w<<<dim3(64), 256, 0, stream>>>(wq, wk, wv, wo, wpk);
  qkv_proj<<<dim3(128, 3), 256, 0, stream>>>(q_in, k_in, v_in, bq, bk, bv, wpk,
                                             qg, kg, vtt);
  attn_fwd<<<dim3(512), 256, 0, stream>>>(qg, kg, vtt, part0, part1, lbuf);
  out_ln<<<dim3(512), 256, 0, stream>>>(part0, part1, lbuf, wpk, bo, gamma, beta, out);
}

// Round 21
// 161.622 us; speedup vs baseline: 1.0763x; 1.0471x over previous
//
#include <hip/hip_runtime.h>
#include <hip/hip_bf16.h>

using bf16 = __hip_bfloat16;
typedef __attribute__((ext_vector_type(8))) short bf16x8;   // 8 bf16 in 4 VGPRs (MFMA A/B frag)
typedef __attribute__((ext_vector_type(4))) short short4v;  // 4 bf16 packed store
typedef __attribute__((ext_vector_type(4))) float f32x4;    // MFMA C/D frag

#define MFMA(a, b, c) __builtin_amdgcn_mfma_f32_16x16x32_bf16((a), (b), (c), 0, 0, 0)

// Problem constants
#define S_LEN 4096
#define D_MODEL 256
#define NH 4
#define HD 64
#define NTOK 8192   // B*S
#define PROW 72     // P-tile LDS row stride in shorts (proven R8)
#define XROW 264    // staged-tile LDS row stride in shorts (proven R12)
#define TROWV 72    // V transpose-buffer row stride (R16)
// R21: exp2 formulation. Q is pre-scaled by 0.125*log2(e) in qkv_proj, and
// the S^T accumulator is initialized to -16*log2(e); then p = exp2(st)
// directly (one v_exp_f32, no sub/mul). Identical math to exp(s-16)
// (static-shift softmax, proven R10; partials add across halves, R18).
#define QSCALE2   0.1803368801f   // 0.125 * log2(e)
#define SM_SHIFT2 23.0831206542f  // 16 * log2(e)

// DTYPE RESOLUTION (R3-R8 evidence): inputs and output are FP32.

static __device__ __forceinline__ short f2bf(float f) {
  bf16 h = __float2bfloat16(f);
  return *reinterpret_cast<short*>(&h);
}

// bf16 bit-pattern (as short) -> float, no addressing.
static __device__ __forceinline__ float bf2f(short s) {
  const unsigned int u = ((unsigned int)(unsigned short)s) << 16;
  return __builtin_bit_cast(float, u);
}

// Async 1KB global->LDS copy, source-swizzled (proven R11).
static __device__ __forceinline__ void stage1k(const bf16* g, short* l, int lane) {
  const int ri = lane >> 3;
  const int ci = lane & 7;
  const bf16* gp = g + ri * 64 + ((ci ^ ri) << 3);
  __builtin_amdgcn_global_load_lds(
      (const __attribute__((address_space(1))) void*)gp,
      (__attribute__((address_space(3))) void*)l, 16, 0, 0);
}

// ---------------------------------------------------------------------------
// Kernel 0: pack the 4 weight matrices into FRAGMENT-MAJOR bf16 (proven R13).
// ---------------------------------------------------------------------------
__global__ __launch_bounds__(256) void pack_w(
    const float* __restrict__ wq, const float* __restrict__ wk,
    const float* __restrict__ wv, const float* __restrict__ wo,
    bf16* __restrict__ wpk) {
  const int mat = blockIdx.x >> 4;
  const int nt  = blockIdx.x & 15;
  const float* W = (mat == 0) ? wq : (mat == 1) ? wk : (mat == 2) ? wv : wo;
  bf16* dst = wpk + ((size_t)(mat * 16 + nt)) * 4096;
#pragma unroll
  for (int it = 0; it < 16; ++it) {
    const int idx = it * 256 + threadIdx.x;
    const int kkt = idx >> 9;
    const int rem = idx & 511;
    const int L = rem >> 3, j = rem & 7;
    const int row = nt * 16 + (L & 15);
    const int col = kkt * 32 + (L >> 4) * 8 + j;
    dst[kkt * 512 + rem] = __float2bfloat16(W[(size_t)row * D_MODEL + col]);
  }
}

// ---------------------------------------------------------------------------
// Kernel 1: QKV projections — R16 version (staged X, packed W, LDS-transpose
// vectorized stores). R21 delta: Q scale now folds log2(e) (QSCALE2) for the
// exp2 softmax formulation in attn_fwd.
// ---------------------------------------------------------------------------
__global__ __launch_bounds__(256) void qkv_proj(
    const float* __restrict__ q_in, const float* __restrict__ k_in, const float* __restrict__ v_in,
    const float* __restrict__ bq_, const float* __restrict__ bk_, const float* __restrict__ bv_,
    const bf16* __restrict__ wpk,
    bf16* __restrict__ qg, bf16* __restrict__ kg, bf16* __restrict__ vtg) {
  const int tid  = threadIdx.x;
  const int wave = tid >> 6;
  const int lane = tid & 63;
  const int quad = lane >> 4;
  const int l16  = lane & 15;
  const int z  = blockIdx.y;
  const int m0 = blockIdx.x * 64;

  const float* X  = (z == 0) ? q_in : (z == 1) ? k_in : v_in;
  const float* Bp = (z == 0) ? bq_  : (z == 1) ? bk_  : bv_;
  const bf16* wp = wpk + (size_t)z * 65536;

  __shared__ short xs[64 * XROW];
  __shared__ short tbuf[256 * TROWV];

#pragma unroll
  for (int it = 0; it < 16; ++it) {
    const int idx = it * 256 + tid;
    const int row = idx >> 6;
    const int c4  = idx & 63;
    const float4 f = *(const float4*)(X + (size_t)(m0 + row) * D_MODEL + c4 * 4);
    short4v s;
    s[0] = f2bf(f.x); s[1] = f2bf(f.y); s[2] = f2bf(f.z); s[3] = f2bf(f.w);
    *(short4v*)&xs[row * XROW + c4 * 4] = s;
  }
  __syncthreads();

  f32x4 acc[4][4] = {};

  if (z < 2) {
    for (int kki = 0; kki < 8; ++kki) {
      const int kk = kki * 32;
      bf16x8 bfr[4];
#pragma unroll
      for (int nt = 0; nt < 4; ++nt)
        bfr[nt] = *(const bf16x8*)(wp + ((wave * 4 + nt) * 8 + kki) * 512 + lane * 8);
#pragma unroll
      for (int ms = 0; ms < 4; ++ms) {
        bf16x8 a = *(const bf16x8*)&xs[(ms * 16 + l16) * XROW + kk + quad * 8];
#pragma unroll
        for (int nt = 0; nt < 4; ++nt) acc[ms][nt] = MFMA(a, bfr[nt], acc[ms][nt]);
      }
    }
    bf16* dst = (z == 0) ? qg : kg;
    const float scale = (z == 0) ? QSCALE2 : 1.0f;  // 1/sqrt(HD)*log2e folded
#pragma unroll
    for (int nt = 0; nt < 4; ++nt) {
      const int o = wave * 64 + nt * 16 + l16;
      const float bias = Bp[o];
#pragma unroll
      for (int ms = 0; ms < 4; ++ms)
#pragma unroll
        for (int r = 0; r < 4; ++r)
          tbuf[(ms * 16 + quad * 4 + r) * XROW + o] =
              f2bf((acc[ms][nt][r] + bias) * scale);
    }
    asm volatile("" ::: "memory");
    const int h = wave;
    const int b_ = m0 >> 12, s0 = m0 & 4095;
    bf16* base = dst + ((size_t)(b_ * NH + h) * S_LEN + s0) * HD;
#pragma unroll
    for (int it = 0; it < 8; ++it) {
      const int s  = it * 8 + (lane >> 3);
      const int ch = (lane & 7) * 8;
      bf16x8 v = *(const bf16x8*)&tbuf[s * XROW + h * 64 + ch];
      *(bf16x8*)(base + (size_t)s * HD + ch) = v;
    }
  } else {
    for (int kki = 0; kki < 8; ++kki) {
      const int kk = kki * 32;
      bf16x8 bx[4];
#pragma unroll
      for (int ts = 0; ts < 4; ++ts)
        bx[ts] = *(const bf16x8*)&xs[(ts * 16 + l16) * XROW + kk + quad * 8];
#pragma unroll
      for (int ot = 0; ot < 4; ++ot) {
        bf16x8 aw = *(const bf16x8*)(wp + ((wave * 4 + ot) * 8 + kki) * 512 + lane * 8);
#pragma unroll
        for (int ts = 0; ts < 4; ++ts) acc[ot][ts] = MFMA(aw, bx[ts], acc[ot][ts]);
      }
    }
#pragma unroll
    for (int ot = 0; ot < 4; ++ot)
#pragma unroll
      for (int r = 0; r < 4; ++r) {
        const int o = wave * 64 + ot * 16 + quad * 4 + r;
        const float bias = Bp[o];
#pragma unroll
        for (int ts = 0; ts < 4; ++ts)
          tbuf[o * TROWV + ts * 16 + l16] = f2bf(acc[ot][ts][r] + bias);
      }
    asm volatile("" ::: "memory");
    const int h = wave;
    const int b_ = m0 >> 12;
    const int jt = (m0 & 4095) >> 6;
    bf16* vbase = vtg + ((size_t)((b_ * NH + h) * (S_LEN / 64) + jt)) * HD * 64;
#pragma unroll
    for (int it = 0; it < 8; ++it) {
      const int hd = it * 8 + (lane >> 3);
      const int jj = (lane & 7) * 8;
      bf16x8 v = *(const bf16x8*)&tbuf[(h * 64 + hd) * TROWV + jj];
      *(bf16x8*)(vbase + (size_t)hd * 64 + jj) = v;
    }
  }
}

// ---------------------------------------------------------------------------
// Kernel 2: flash attention — R18 structure (measured best, 60 us): 4-wave
// blocks, 2 q-sets/wave, KV-split-2, 2-subtile rounds, grid 512.
// R21 delta: exp2 softmax — S^T accumulator initialized to -16*log2e
// (Q pre-scaled by log2e), so p = v_exp_f32(st) with NO sub/mul in the
// hot loop. Identical math; saves 64 VALU ops per wave-round.
// Carried (proven): XCD-aware bh=blockIdx&7, global_load_lds staging w/
// source swizzle, barrier-free wave-private P round-trip, PROW=72.
// Parallelism-shape ledger: R14 (2w/1sub) 109us, R15 (4w/1blk-CU) 79us,
// R19 (2w/4blk-CU) 67us, R18 (4w/2sub/2blk-CU) 61us — do not reshape again.
// ---------------------------------------------------------------------------
__global__ __launch_bounds__(256) void attn_fwd(
    const bf16* qg, const bf16* kg, const bf16* vtg,
    bf16* part0, bf16* part1, float* lbuf) {
  const int wave = threadIdx.x >> 6;
  const int lane = threadIdx.x & 63;
  const int quad = lane >> 4;
  const int l16  = lane & 15;
  const int bh   = blockIdx.x & 7;        // XCD-aligned under %8 round-robin
  const int half = (blockIdx.x >> 3) & 1; // key range half
  const int q0   = (blockIdx.x >> 4) * 128;

  const bf16* qb = qg  + (size_t)bh * S_LEN * HD;
  const bf16* kb = kg  + (size_t)bh * S_LEN * HD;
  const bf16* vb = vtg + (size_t)bh * S_LEN * HD;  // tile-major: 64 x 4096

  __shared__ short kbuf[2][2 * 4096];   // 16KB per buffer
  __shared__ short vbuf[2][2 * 4096];
  __shared__ short p_lds[4 * 16 * PROW];

  // Two 16-row Q fragment sets per wave.
  bf16x8 qf[2][2];
#pragma unroll
  for (int qs = 0; qs < 2; ++qs) {
    const bf16* qrow = qb + (size_t)(q0 + wave * 32 + qs * 16 + l16) * HD;
    qf[qs][0] = *(const bf16x8*)(qrow + quad * 8);
    qf[qs][1] = *(const bf16x8*)(qrow + 32 + quad * 8);
  }

  float l_acc[2] = {0.f, 0.f};
  f32x4 oT[2][4] = {};
  const int pb = wave * (16 * PROW) + l16 * PROW;
  const int sw = l16 & 7;
  const int c0 = wave * 2;
  const f32x4 sinit = {-SM_SHIFT2, -SM_SHIFT2, -SM_SHIFT2, -SM_SHIFT2};

#define STAGE_ROUND(b, r)                                                   \
  {                                                                         \
    _Pragma("unroll")                                                       \
    for (int sub = 0; sub < 2; ++sub) {                                     \
      const bf16* kt = kb + (size_t)(2 * (r) + sub) * 4096;                 \
      const bf16* vt_ = vb + (size_t)(2 * (r) + sub) * 4096;                \
      _Pragma("unroll")                                                     \
      for (int q = 0; q < 2; ++q) {                                         \
        stage1k(kt + (c0 + q) * 512, &kbuf[b][sub * 4096 + (c0 + q) * 512], lane); \
        stage1k(vt_ + (c0 + q) * 512, &vbuf[b][sub * 4096 + (c0 + q) * 512], lane); \
      }                                                                     \
    }                                                                       \
  }

  const int t0 = half * 16, t1 = t0 + 16;   // 16 rounds = 2048 keys
  STAGE_ROUND(0, t0)

  for (int t = t0; t < t1; ++t) {
    const int buf = t & 1;
    __syncthreads();
    if (t + 1 < t1) STAGE_ROUND(buf ^ 1, t + 1)

#pragma unroll
    for (int sub = 0; sub < 2; ++sub) {
      const short* kB = &kbuf[buf][sub * 4096];
      const short* vB = &vbuf[buf][sub * 4096];

      // K fragments once, feed both q-sets.
      bf16x8 kf[4][2];
#pragma unroll
      for (int ct = 0; ct < 4; ++ct) {
        const int rbase = (ct * 16 + l16) * 64;
        kf[ct][0] = *(const bf16x8*)&kB[rbase + ((quad ^ sw) << 3)];
        kf[ct][1] = *(const bf16x8*)&kB[rbase + (((quad + 4) ^ sw) << 3)];
      }

      // Accumulator pre-biased with -16*log2e: st = s*log2e - 16*log2e.
      f32x4 st[2][4] = {{sinit, sinit, sinit, sinit},
                        {sinit, sinit, sinit, sinit}};
#pragma unroll
      for (int qs = 0; qs < 2; ++qs)
#pragma unroll
        for (int ct = 0; ct < 4; ++ct) {
          st[qs][ct] = MFMA(kf[ct][0], qf[qs][0], st[qs][ct]);
          st[qs][ct] = MFMA(kf[ct][1], qf[qs][1], st[qs][ct]);
        }

      // V fragments once, feed both q-sets.
      bf16x8 vf[4][2];
#pragma unroll
      for (int tt = 0; tt < 4; ++tt) {
        const int rbase = (tt * 16 + l16) * 64;
        vf[tt][0] = *(const bf16x8*)&vB[rbase + ((quad ^ sw) << 3)];
        vf[tt][1] = *(const bf16x8*)&vB[rbase + (((quad + 4) ^ sw) << 3)];
      }

#pragma unroll
      for (int qs = 0; qs < 2; ++qs) {
#pragma unroll
        for (int ct = 0; ct < 4; ++ct)
#pragma unroll
          for (int r = 0; r < 4; ++r) {
            const float p = __builtin_amdgcn_exp2f(st[qs][ct][r]);
            st[qs][ct][r] = p;
            l_acc[qs] += p;
          }

        asm volatile("" ::: "memory");  // WAR
#pragma unroll
        for (int ct = 0; ct < 4; ++ct) {
          short4v pk;
          pk[0] = f2bf(st[qs][ct][0]);
          pk[1] = f2bf(st[qs][ct][1]);
          pk[2] = f2bf(st[qs][ct][2]);
          pk[3] = f2bf(st[qs][ct][3]);
          *(short4v*)&p_lds[pb + ct * 16 + quad * 4] = pk;
        }
        asm volatile("" ::: "memory");  // RAW
        bf16x8 bp0 = *(const bf16x8*)&p_lds[pb + quad * 8];
        bf16x8 bp1 = *(const bf16x8*)&p_lds[pb + 32 + quad * 8];

#pragma unroll
        for (int tt = 0; tt < 4; ++tt) {
          oT[qs][tt] = MFMA(vf[tt][0], bp0, oT[qs][tt]);
          oT[qs][tt] = MFMA(vf[tt][1], bp1, oT[qs][tt]);
        }
      }
    }
  }
#undef STAGE_ROUND

  // Emit UNNORMALIZED partials (static shift -> partials add across halves).
  bf16* part = half ? part1 : part0;
  const int b_ = bh >> 2, h = bh & 3;
#pragma unroll
  for (int qs = 0; qs < 2; ++qs) {
    float l = l_acc[qs];
    l += __shfl_xor(l, 16);
    l += __shfl_xor(l, 32);
    const int srow = q0 + wave * 32 + qs * 16 + l16;
    if (quad == 0)  // one writer per token
      lbuf[half * 32768 + bh * 4096 + srow] = l;
    bf16* ob = part + ((size_t)(b_ * S_LEN + srow)) * D_MODEL + h * HD;
#pragma unroll
    for (int t = 0; t < 4; ++t) {
      short4v pk;
#pragma unroll
      for (int r = 0; r < 4; ++r) pk[r] = f2bf(oT[qs][t][r]);
      *(short4v*)(ob + t * 16 + quad * 4) = pk;
    }
  }
}

// ---------------------------------------------------------------------------
// Kernel 3: out-projection + LayerNorm with FUSED partial combine (R19,
// kept): staging reads part0+part1 and normalizes by 1/(l0+l1).
// GEMM + LN parts unchanged (proven R13).
// ---------------------------------------------------------------------------
__global__ __launch_bounds__(256) void out_ln(
    const bf16* __restrict__ part0, const bf16* __restrict__ part1,
    const float* __restrict__ lbuf, const bf16* __restrict__ wpk,
    const float* __restrict__ bo_, const float* __restrict__ gamma,
    const float* __restrict__ beta, float* __restrict__ out) {
  const int tid = threadIdx.x;
  const int wave = tid >> 6;
  const int lane = tid & 63;
  const int quad = lane >> 4;
  const int l16  = lane & 15;
  const int t0 = blockIdx.x * 16;
  const bf16* wp = wpk + (size_t)3 * 65536;

  __shared__ short as_[16 * XROW];
  __shared__ float ybuf[16 * 256];
  __shared__ float mu_s[16], rs_s[16];

  // Stage + combine: attn = (P0+P1) / (l0+l1), per 16B chunk.
#pragma unroll
  for (int it = 0; it < 2; ++it) {
    const int idx = it * 256 + tid;
    const int row = idx >> 5;
    const int c8  = idx & 31;
    const int token = t0 + row;
    const int h = c8 >> 3;
    const int bh = (token >> 12) * NH + h;
    const int s = token & 4095;
    const float li = 1.0f / (lbuf[bh * 4096 + s] + lbuf[32768 + bh * 4096 + s]);
    const size_t gidx = (size_t)token * D_MODEL + c8 * 8;
    bf16x8 a = *(const bf16x8*)(part0 + gidx);
    bf16x8 b = *(const bf16x8*)(part1 + gidx);
    bf16x8 o;
#pragma unroll
    for (int j = 0; j < 8; ++j)
      o[j] = f2bf((bf2f(a[j]) + bf2f(b[j])) * li);
    *(bf16x8*)&as_[row * XROW + c8 * 8] = o;
  }
  __syncthreads();

  f32x4 acc[4] = {};
  for (int kki = 0; kki < 8; ++kki) {
    const int kk = kki * 32;
    bf16x8 a = *(const bf16x8*)&as_[l16 * XROW + kk + quad * 8];
#pragma unroll
    for (int nt = 0; nt < 4; ++nt) {
      bf16x8 b = *(const bf16x8*)(wp + ((wave * 4 + nt) * 8 + kki) * 512 + lane * 8);
      acc[nt] = MFMA(a, b, acc[nt]);
    }
  }
#pragma unroll
  for (int nt = 0; nt < 4; ++nt) {
    const int o = wave * 64 + nt * 16 + l16;
    const float bias = bo_[o];
#pragma unroll
    for (int r = 0; r < 4; ++r) ybuf[(quad * 4 + r) * 256 + o] = acc[nt][r] + bias;
  }
  __syncthreads();

#pragma unroll
  for (int rr = 0; rr < 4; ++rr) {
    const int row = wave * 4 + rr;
    float s1 = 0.f, s2 = 0.f;
#pragma unroll
    for (int c = 0; c < 4; ++c) {
      const float v = ybuf[row * 256 + c * 64 + lane];
      s1 += v;
      s2 += v * v;
    }
#pragma unroll
    for (int m = 32; m >= 1; m >>= 1) {
      s1 += __shfl_xor(s1, m);
      s2 += __shfl_xor(s2, m);
    }
    if (lane == 0) {
      const float mu = s1 * (1.f / 256.f);
      const float var = s2 * (1.f / 256.f) - mu * mu;
      mu_s[row] = mu;
      rs_s[row] = rsqrtf(var + 1e-5f);
    }
  }
  __syncthreads();

  const float g  = gamma[tid];
  const float be = beta[tid];
#pragma unroll 4
  for (int row = 0; row < 16; ++row) {
    const float v = ybuf[row * 256 + tid];
    const float o = (v - mu_s[row]) * rs_s[row] * g + be;
    out[(size_t)(t0 + row) * D_MODEL + tid] = o;
  }
}

// ---------------------------------------------------------------------------
extern "C" void kernel_launch(void* const* d_in, const int* in_sizes, int n_in,
                              void* d_out, int out_size, void* d_ws, size_t ws_size,
                              hipStream_t stream) {
  const float* q_in  = (const float*)d_in[0];
  const float* k_in  = (const float*)d_in[1];
  const float* v_in  = (const float*)d_in[2];
  const float* wq    = (const float*)d_in[3];
  const float* bq    = (const float*)d_in[4];
  const float* wk    = (const float*)d_in[5];
  const float* bk    = (const float*)d_in[6];
  const float* wv    = (const float*)d_in[7];
  const float* bv    = (const float*)d_in[8];
  const float* wo    = (const float*)d_in[9];
  const float* bo    = (const float*)d_in[10];
  const float* gamma = (const float*)d_in[11];
  const float* beta  = (const float*)d_in[12];
  float* out = (float*)d_out;

  // qg/kg staged in d_out (proven). ws: vtt 4MB | part0 4MB | part1 4MB |
  // wpk 512KB | lbuf 256KB = 12.75 MB (proven fits).
  const size_t SEG = (size_t)NTOK * D_MODEL;  // 2,097,152 elements
  bf16* qg    = (bf16*)d_out;
  bf16* kg    = (bf16*)d_out + SEG;
  bf16* vtt   = (bf16*)d_ws;
  bf16* part0 = (bf16*)d_ws + SEG;
  bf16* part1 = (bf16*)d_ws + 2 * SEG;
  bf16* wpk   = (bf16*)d_ws + 3 * SEG;  // 262144 elements
  float* lbuf = (float*)((bf16*)d_ws + 3 * SEG + 262144);  // 65536 floats

  pack_w<<<dim3(64), 256, 0, stream>>>(wq, wk, wv, wo, wpk);
  qkv_proj<<<dim3(128, 3), 256, 0, stream>>>(q_in, k_in, v_in, bq, bk, bv, wpk,
                                             qg, kg, vtt);
  attn_fwd<<<dim3(512), 256, 0, stream>>>(qg, kg, vtt, part0, part1, lbuf);
  out_ln<<<dim3(512), 256, 0, stream>>>(part0, part1, lbuf, wpk, bo, gamma, beta, out);
}